// Round 11
// baseline (500.786 us; speedup 1.0000x reference)
//
#include <hip/hip_runtime.h>
#include <hip/hip_fp16.h>

#define NN 100000
#define EE 3200000
#define HH 64
#define FINN 6
#define FOUT 5
#define NGNB 50000
#define NBUK 391   // buckets of 256 nodes: bucket = dst >> 8
#define NBH 256    // blocks for hist/scatter passes (1 block/CU)

static inline int cdiv(int a, int b) { return (a + b - 1) / b; }
static inline size_t alignup(size_t x) { return (x + 255) & ~(size_t)255; }

// Pass A: per-block bucket histogram (LDS), write blockhist[block][NBUK]
__global__ __launch_bounds__(1024) void k_histA(const int* __restrict__ dst,
                                                int* __restrict__ blockhist) {
    __shared__ int hist[NBUK];
    int t = threadIdx.x;
    if (t < NBUK) hist[t] = 0;
    __syncthreads();
    for (int e = blockIdx.x * 1024 + t; e < EE; e += NBH * 1024)
        atomicAdd(&hist[dst[e] >> 8], 1);
    __syncthreads();
    if (t < NBUK) blockhist[blockIdx.x * NBUK + t] = hist[t];
}

// Pass B: turn blockhist into per-(block,bucket) bases; bucket_ptr = bucket starts
__global__ void k_scanB(int* __restrict__ blockhist, int* __restrict__ bucket_ptr) {
    __shared__ int sh[512];
    int t = threadIdx.x;
    int total = 0;
    if (t < NBUK)
        for (int b = 0; b < NBH; ++b) total += blockhist[b * NBUK + t];
    sh[t] = (t < NBUK) ? total : 0;
    __syncthreads();
    for (int off = 1; off < 512; off <<= 1) {
        int a = (t >= off) ? sh[t - off] : 0;
        __syncthreads();
        sh[t] += a;
        __syncthreads();
    }
    if (t < NBUK) {
        int base = sh[t] - total;  // exclusive
        bucket_ptr[t] = base;
        if (t == 0) bucket_ptr[NBUK] = EE;
        int run = base;
        for (int b = 0; b < NBH; ++b) {
            int c = blockhist[b * NBUK + t];
            blockhist[b * NBUK + t] = run;
            run += c;
        }
    }
}

// Pass C: scatter edges into bucket-grouped ebuk = {(dl<<17)|src, w}
__global__ __launch_bounds__(1024) void k_scatC(const int* __restrict__ src,
                                                const int* __restrict__ dst,
                                                const float* __restrict__ w,
                                                const int* __restrict__ blockhist,
                                                int2* __restrict__ ebuk) {
    __shared__ int cur[NBUK];
    int t = threadIdx.x;
    if (t < NBUK) cur[t] = blockhist[blockIdx.x * NBUK + t];
    __syncthreads();
    for (int e = blockIdx.x * 1024 + t; e < EE; e += NBH * 1024) {
        int d = dst[e];
        int k = d >> 8, dl = d & 255;
        int pos = atomicAdd(&cur[k], 1);
        int2 p;
        p.x = (dl << 17) | src[e];
        p.y = __float_as_int(w[e]);
        ebuk[pos] = p;
    }
}

// Pass D: per-bucket — one u64 LDS atomic per edge packs {count<<40, wsum fixed
// 2^-24}; scan; CSR scatter. epack.x = src*128 (fp16-row byte offset).
__global__ __launch_bounds__(1024) void k_csrD(const int2* __restrict__ ebuk,
                                               const int* __restrict__ bucket_ptr,
                                               int* __restrict__ row_ptr,
                                               float* __restrict__ dinv,
                                               int2* __restrict__ epack) {
    __shared__ unsigned long long pk[256];
    __shared__ int sh[256];
    __shared__ int cursor[256];
    int t = threadIdx.x;
    int k = blockIdx.x;
    if (t < 256) pk[t] = (1ULL << 24);  // self-loop weight 1.0 (fixed point), count 0
    __syncthreads();
    int r0 = bucket_ptr[k], r1 = bucket_ptr[k + 1];
    for (int e = r0 + t; e < r1; e += 1024) {
        int2 p = ebuk[e];
        int dl = (p.x >> 17) & 255;
        unsigned long long add =
            (1ULL << 40) |
            (unsigned long long)(__int_as_float(p.y) * 16777216.0f);
        atomicAdd(&pk[dl], add);
    }
    __syncthreads();
    int c = 0;
    if (t < 256) { c = (int)(pk[t] >> 40); sh[t] = c; }
    __syncthreads();
    for (int off = 1; off < 256; off <<= 1) {
        int a = (t < 256 && t >= off) ? sh[t - off] : 0;
        __syncthreads();
        if (t < 256) sh[t] += a;
        __syncthreads();
    }
    if (t < 256) {
        int gstart = r0 + sh[t] - c;
        cursor[t] = gstart;
        int node = k * 256 + t;
        if (node < NN) {
            float wsum = (float)(pk[t] & 0xFFFFFFFFFFULL) * (1.0f / 16777216.0f);
            row_ptr[node] = gstart;
            dinv[node] = rsqrtf(wsum);
            if (node == NN - 1) row_ptr[NN] = EE;
        }
    }
    __syncthreads();
    for (int e = r0 + t; e < r1; e += 1024) {
        int2 p = ebuk[e];
        int dl = (p.x >> 17) & 255;
        int pos = atomicAdd(&cursor[dl], 1);
        int2 q;
        q.x = (p.x & 0x1FFFF) << 7;  // src * 128 bytes
        q.y = p.y;
        epack[pos] = q;
    }
}

// vfs[i,f] = vf[i,f] * dinv[i]
__global__ void k_vfs(const float* __restrict__ vf, const float* __restrict__ dinv,
                      float* __restrict__ vfs) {
    int i = blockIdx.x * 256 + threadIdx.x;
    if (i >= NN) return;
    float di = dinv[i];
#pragma unroll
    for (int f = 0; f < FINN; ++f) vfs[i * FINN + f] = vf[i * FINN + f] * di;
}

// layer-1 aggregation: acc6[i] = dinv[i] * (vfs[i] + sum w * vfs[s])
__global__ void k_gather6(const float* __restrict__ vfs, const float* __restrict__ dinv,
                          const int* __restrict__ rp, const int2* __restrict__ epack,
                          float* __restrict__ acc6) {
    int i = blockIdx.x * 256 + threadIdx.x;
    if (i >= NN) return;
    float av[FINN];
#pragma unroll
    for (int f = 0; f < FINN; ++f) av[f] = vfs[i * FINN + f];
    int e1 = rp[i + 1];
    for (int e = rp[i]; e < e1; ++e) {
        int2 p = epack[e];
        int s = p.x >> 7;
        float wn = __int_as_float(p.y);
#pragma unroll
        for (int f = 0; f < FINN; ++f) av[f] += vfs[s * FINN + f] * wn;
    }
    float di = dinv[i];
#pragma unroll
    for (int f = 0; f < FINN; ++f) acc6[i * FINN + f] = av[f] * di;
}

// Fused 64-dim layer: wave per node, 8 nodes/block.
// Quarter-wave gather: lane loads uint2 (4 halves) at feature-quad fq=lane&15;
// quarter qf=lane>>4 takes edge j+qf -> ONE VMEM fetches 4 rows. Edge records
// staged in wave-private LDS (broadcast ds_read_b64, dummy {0,w=0} padding).
// Butterfly shfl (^16, ^32) combines quarters. Epilogue: in-LDS 64->64 GEMM +
// bias + sigmoid; HEAD fuses the 64->5 head and writes out directly.
template <bool HEAD>
__global__ __launch_bounds__(512) void k_layer64f(
    const __half* __restrict__ yin, const float* __restrict__ dinv,
    const int* __restrict__ rp, const int2* __restrict__ epack,
    const float* __restrict__ W, const float* __restrict__ b,
    __half* __restrict__ yout,
    const float* __restrict__ Wl, const float* __restrict__ bl,
    float* __restrict__ outp) {
    __shared__ float Wsh[HH * HH];   // 16 KB
    __shared__ float bsh[HH];
    __shared__ float aggsh[8 * HH];
    __shared__ float Wlsh[HH * FOUT];
    __shared__ float blsh[FOUT];
    __shared__ int2 estage[8 * 64];  // 512 B wave-private edge staging per wave
    for (int t = threadIdx.x; t < HH * HH; t += 512) Wsh[t] = W[t];
    if (threadIdx.x < HH) bsh[threadIdx.x] = b[threadIdx.x];
    if (HEAD) {
        for (int t = threadIdx.x; t < HH * FOUT; t += 512) Wlsh[t] = Wl[t];
        if (threadIdx.x < FOUT) blsh[threadIdx.x] = bl[threadIdx.x];
    }

    int wv = threadIdx.x >> 6, lane = threadIdx.x & 63;
    int i = blockIdx.x * 8 + wv;  // grids divide exactly: no partial blocks
    int qf = lane >> 4, fq = lane & 15;
    unsigned fq8 = (unsigned)fq * 8u;
    float di = dinv[i];
    const char* ybp = (const char*)yin;
    float a0 = 0.0f, a1 = 0.0f, a2 = 0.0f, a3 = 0.0f;
    if (qf == 0) {  // self loop (coeff 1), quarter 0 only
        uint2 v = *(const uint2*)(ybp + (size_t)i * 128 + fq8);
        __half2 p0 = *(__half2*)&v.x, p1 = *(__half2*)&v.y;
        a0 = __half2float(p0.x);
        a1 = __half2float(p0.y);
        a2 = __half2float(p1.x);
        a3 = __half2float(p1.y);
    }
    int e0 = __builtin_amdgcn_readfirstlane(rp[i]);
    int e1 = __builtin_amdgcn_readfirstlane(rp[i + 1]);
    int2* sw = &estage[wv * 64];
    for (int base = e0; base < e1; base += 64) {
        int n = e1 - base;
        if (n > 64) n = 64;
        int n4 = (n + 3) & ~3;
        if (lane < n) sw[lane] = epack[base + lane];       // coalesced 512B/wave
        else if (lane < n4) sw[lane] = make_int2(0, 0);    // dummy: row 0, w=0
        int j = 0;
        for (; j + 16 <= n4; j += 16) {  // 4 groups = 16 rows in flight, 4 VMEM
            int2 r0 = sw[j + 0 + qf];
            int2 r1 = sw[j + 4 + qf];
            int2 r2 = sw[j + 8 + qf];
            int2 r3 = sw[j + 12 + qf];
            uint2 v0 = *(const uint2*)(ybp + ((unsigned)r0.x + fq8));
            uint2 v1 = *(const uint2*)(ybp + ((unsigned)r1.x + fq8));
            uint2 v2 = *(const uint2*)(ybp + ((unsigned)r2.x + fq8));
            uint2 v3 = *(const uint2*)(ybp + ((unsigned)r3.x + fq8));
            float w0 = __int_as_float(r0.y), w1 = __int_as_float(r1.y);
            float w2 = __int_as_float(r2.y), w3 = __int_as_float(r3.y);
            __half2 h00 = *(__half2*)&v0.x, h01 = *(__half2*)&v0.y;
            __half2 h10 = *(__half2*)&v1.x, h11 = *(__half2*)&v1.y;
            __half2 h20 = *(__half2*)&v2.x, h21 = *(__half2*)&v2.y;
            __half2 h30 = *(__half2*)&v3.x, h31 = *(__half2*)&v3.y;
            a0 = fmaf(__half2float(h00.x), w0, a0);
            a1 = fmaf(__half2float(h00.y), w0, a1);
            a2 = fmaf(__half2float(h01.x), w0, a2);
            a3 = fmaf(__half2float(h01.y), w0, a3);
            a0 = fmaf(__half2float(h10.x), w1, a0);
            a1 = fmaf(__half2float(h10.y), w1, a1);
            a2 = fmaf(__half2float(h11.x), w1, a2);
            a3 = fmaf(__half2float(h11.y), w1, a3);
            a0 = fmaf(__half2float(h20.x), w2, a0);
            a1 = fmaf(__half2float(h20.y), w2, a1);
            a2 = fmaf(__half2float(h21.x), w2, a2);
            a3 = fmaf(__half2float(h21.y), w2, a3);
            a0 = fmaf(__half2float(h30.x), w3, a0);
            a1 = fmaf(__half2float(h30.y), w3, a1);
            a2 = fmaf(__half2float(h31.x), w3, a2);
            a3 = fmaf(__half2float(h31.y), w3, a3);
        }
        for (; j < n4; j += 4) {  // remaining groups of 4 edges
            int2 r = sw[j + qf];
            uint2 v = *(const uint2*)(ybp + ((unsigned)r.x + fq8));
            float wn = __int_as_float(r.y);
            __half2 h0 = *(__half2*)&v.x, h1 = *(__half2*)&v.y;
            a0 = fmaf(__half2float(h0.x), wn, a0);
            a1 = fmaf(__half2float(h0.y), wn, a1);
            a2 = fmaf(__half2float(h1.x), wn, a2);
            a3 = fmaf(__half2float(h1.y), wn, a3);
        }
    }
    // butterfly combine across the 4 quarter-waves
    a0 += __shfl(a0, lane ^ 16, 64);
    a1 += __shfl(a1, lane ^ 16, 64);
    a2 += __shfl(a2, lane ^ 16, 64);
    a3 += __shfl(a3, lane ^ 16, 64);
    a0 += __shfl(a0, lane ^ 32, 64);
    a1 += __shfl(a1, lane ^ 32, 64);
    a2 += __shfl(a2, lane ^ 32, 64);
    a3 += __shfl(a3, lane ^ 32, 64);
    __syncthreads();  // Wsh/bsh staged
    if (lane < 16)
        ((float4*)&aggsh[wv * HH])[fq] =
            make_float4(a0 * di, a1 * di, a2 * di, a3 * di);
    __syncthreads();
    float o = bsh[lane];
    const float4* a4 = (const float4*)&aggsh[wv * HH];
#pragma unroll
    for (int f0 = 0; f0 < HH; f0 += 4) {
        float4 av = a4[f0 >> 2];  // broadcast read
        o += av.x * Wsh[(f0 + 0) * HH + lane];
        o += av.y * Wsh[(f0 + 1) * HH + lane];
        o += av.z * Wsh[(f0 + 2) * HH + lane];
        o += av.w * Wsh[(f0 + 3) * HH + lane];
    }
    float sig = 1.0f / (1.0f + __expf(-o));
    if (!HEAD) {
        yout[(size_t)i * HH + lane] = __float2half(sig * di);  // scaled y
    } else {
        aggsh[wv * HH + lane] = sig;  // unscaled, own-wave slice only
        __syncthreads();
        if (lane < FOUT) {
            float s = blsh[lane];
            const float* ar = &aggsh[wv * HH];
#pragma unroll
            for (int f = 0; f < HH; ++f) s += ar[f] * Wlsh[f * FOUT + lane];
            outp[(size_t)i * FOUT + lane] = s;
        }
    }
}

// out[i,:] = sigmoid(acc6[i,:FI] @ W + b) * dinv  (layer 1 only)
template <int FI>
__global__ void k_gemm_sig(const float* __restrict__ x, const float* __restrict__ W,
                           const float* __restrict__ b, const float* __restrict__ dinv,
                           __half* __restrict__ out) {
    __shared__ float Wsl[FI * 64];
    __shared__ float bsl[64];
    for (int t = threadIdx.x; t < FI * 64; t += 256) Wsl[t] = W[t];
    if (threadIdx.x < 64) bsl[threadIdx.x] = b[threadIdx.x];
    __syncthreads();
    int wave = (blockIdx.x * 256 + threadIdx.x) >> 6;
    int lane = threadIdx.x & 63;
    if (wave >= NN) return;
    const float* xr = x + (size_t)wave * FI;
    float s = bsl[lane];
#pragma unroll
    for (int f = 0; f < FI; ++f) s += xr[f] * Wsl[f * 64 + lane];
    float sig = 1.0f / (1.0f + __expf(-s));
    sig *= dinv[wave];
    out[(size_t)wave * HH + lane] = __float2half(sig);
}

extern "C" void kernel_launch(void* const* d_in, const int* in_sizes, int n_in,
                              void* d_out, int out_size, void* d_ws, size_t ws_size,
                              hipStream_t stream) {
    (void)in_sizes; (void)n_in; (void)out_size; (void)ws_size;
    const float* vf = (const float*)d_in[0];
    const int* edges = (const int*)d_in[1];
    const float* w = (const float*)d_in[2];
    const float* W1 = (const float*)d_in[3];
    const float* b1 = (const float*)d_in[4];
    const float* W2 = (const float*)d_in[5];
    const float* b2 = (const float*)d_in[6];
    const float* W3 = (const float*)d_in[7];
    const float* b3 = (const float*)d_in[8];
    const float* W4 = (const float*)d_in[9];
    const float* b4 = (const float*)d_in[10];
    const float* Wl = (const float*)d_in[11];
    const float* bl = (const float*)d_in[12];
    float* out = (float*)d_out;

    const int* src = edges;
    const int* dst = edges + EE;

    // workspace: 256B-aligned regions
    char* base = (char*)d_ws;
    size_t off = 0;
    float* dinv = (float*)(base + off);      off = alignup(off + sizeof(float) * NN);
    int* row_ptr = (int*)(base + off);       off = alignup(off + sizeof(int) * (NN + 1));
    int* bucket_ptr = (int*)(base + off);    off = alignup(off + sizeof(int) * (NBUK + 1));
    int* blockhist = (int*)(base + off);     off = alignup(off + sizeof(int) * NBH * NBUK);
    int2* ebuk = (int2*)(base + off);        off = alignup(off + sizeof(int2) * EE);
    int2* epack = (int2*)(base + off);       off = alignup(off + sizeof(int2) * EE);
    float* acc6 = (float*)(base + off);      off = alignup(off + sizeof(float) * (size_t)NN * FINN);
    float* vfs = (float*)(base + off);       off = alignup(off + sizeof(float) * (size_t)NN * FINN);
    __half* ya = (__half*)(base + off);      off = alignup(off + sizeof(__half) * (size_t)NN * HH);
    __half* yb = (__half*)(base + off);      off = alignup(off + sizeof(__half) * (size_t)NN * HH);

    // CSR build via two-level bucket sort (no global atomics)
    k_histA<<<NBH, 1024, 0, stream>>>(dst, blockhist);
    k_scanB<<<1, 512, 0, stream>>>(blockhist, bucket_ptr);
    k_scatC<<<NBH, 1024, 0, stream>>>(src, dst, w, blockhist, ebuk);
    k_csrD<<<NBUK, 1024, 0, stream>>>(ebuk, bucket_ptr, row_ptr, dinv, epack);

    // scaled input features
    k_vfs<<<cdiv(NN, 256), 256, 0, stream>>>(vf, dinv, vfs);

    // layer 1: gather(6) -> gemm+sigmoid (scaled -> ya)
    k_gather6<<<cdiv(NN, 256), 256, 0, stream>>>(vfs, dinv, row_ptr, epack, acc6);
    k_gemm_sig<FINN><<<cdiv(NN * 64, 256), 256, 0, stream>>>(acc6, W1, b1, dinv, ya);

    // layers 2,3 fused (scaled), ping-pong; layer 4 fused + head, 50k nodes only
    k_layer64f<false><<<NN / 8, 512, 0, stream>>>(ya, dinv, row_ptr, epack, W2, b2, yb,
                                                  nullptr, nullptr, nullptr);
    k_layer64f<false><<<NN / 8, 512, 0, stream>>>(yb, dinv, row_ptr, epack, W3, b3, ya,
                                                  nullptr, nullptr, nullptr);
    k_layer64f<true><<<NGNB / 8, 512, 0, stream>>>(ya, dinv, row_ptr, epack, W4, b4, nullptr,
                                                   Wl, bl, out);
}

// Round 12
// 469.241 us; speedup vs baseline: 1.0672x; 1.0672x over previous
//
#include <hip/hip_runtime.h>
#include <hip/hip_fp16.h>

#define NN 100000
#define EE 3200000
#define HH 64
#define FINN 6
#define FOUT 5
#define NGNB 50000
#define NBUK 391   // buckets of 256 nodes: bucket = dst >> 8
#define NBH 256    // blocks for hist/scatter passes (1 block/CU)

static inline int cdiv(int a, int b) { return (a + b - 1) / b; }
static inline size_t alignup(size_t x) { return (x + 255) & ~(size_t)255; }

// Pass A: per-block bucket histogram (LDS), write blockhist[block][NBUK]
__global__ __launch_bounds__(1024) void k_histA(const int* __restrict__ dst,
                                                int* __restrict__ blockhist) {
    __shared__ int hist[NBUK];
    int t = threadIdx.x;
    if (t < NBUK) hist[t] = 0;
    __syncthreads();
    for (int e = blockIdx.x * 1024 + t; e < EE; e += NBH * 1024)
        atomicAdd(&hist[dst[e] >> 8], 1);
    __syncthreads();
    if (t < NBUK) blockhist[blockIdx.x * NBUK + t] = hist[t];
}

// Pass B: turn blockhist into per-(block,bucket) bases; bucket_ptr = bucket starts
__global__ void k_scanB(int* __restrict__ blockhist, int* __restrict__ bucket_ptr) {
    __shared__ int sh[512];
    int t = threadIdx.x;
    int total = 0;
    if (t < NBUK)
        for (int b = 0; b < NBH; ++b) total += blockhist[b * NBUK + t];
    sh[t] = (t < NBUK) ? total : 0;
    __syncthreads();
    for (int off = 1; off < 512; off <<= 1) {
        int a = (t >= off) ? sh[t - off] : 0;
        __syncthreads();
        sh[t] += a;
        __syncthreads();
    }
    if (t < NBUK) {
        int base = sh[t] - total;  // exclusive
        bucket_ptr[t] = base;
        if (t == 0) bucket_ptr[NBUK] = EE;
        int run = base;
        for (int b = 0; b < NBH; ++b) {
            int c = blockhist[b * NBUK + t];
            blockhist[b * NBUK + t] = run;
            run += c;
        }
    }
}

// Pass C: scatter edges into bucket-grouped ebuk = {(dl<<17)|src, w}
__global__ __launch_bounds__(1024) void k_scatC(const int* __restrict__ src,
                                                const int* __restrict__ dst,
                                                const float* __restrict__ w,
                                                const int* __restrict__ blockhist,
                                                int2* __restrict__ ebuk) {
    __shared__ int cur[NBUK];
    int t = threadIdx.x;
    if (t < NBUK) cur[t] = blockhist[blockIdx.x * NBUK + t];
    __syncthreads();
    for (int e = blockIdx.x * 1024 + t; e < EE; e += NBH * 1024) {
        int d = dst[e];
        int k = d >> 8, dl = d & 255;
        int pos = atomicAdd(&cur[k], 1);
        int2 p;
        p.x = (dl << 17) | src[e];
        p.y = __float_as_int(w[e]);
        ebuk[pos] = p;
    }
}

// Pass D: per-bucket — one u64 LDS atomic per edge packs {count<<40, wsum fixed
// 2^-24}; scan; CSR scatter. epack.x = src*128 (fp16-row byte offset).
// Tail: computes vfs = vf * dinv for this bucket's 256 nodes (fused k_vfs).
__global__ __launch_bounds__(1024) void k_csrD(const int2* __restrict__ ebuk,
                                               const int* __restrict__ bucket_ptr,
                                               int* __restrict__ row_ptr,
                                               float* __restrict__ dinv,
                                               int2* __restrict__ epack,
                                               const float* __restrict__ vf,
                                               float* __restrict__ vfs) {
    __shared__ unsigned long long pk[256];
    __shared__ int sh[256];
    __shared__ int cursor[256];
    int t = threadIdx.x;
    int k = blockIdx.x;
    if (t < 256) pk[t] = (1ULL << 24);  // self-loop weight 1.0 (fixed point), count 0
    __syncthreads();
    int r0 = bucket_ptr[k], r1 = bucket_ptr[k + 1];
    for (int e = r0 + t; e < r1; e += 1024) {
        int2 p = ebuk[e];
        int dl = (p.x >> 17) & 255;
        unsigned long long add =
            (1ULL << 40) |
            (unsigned long long)(__int_as_float(p.y) * 16777216.0f);
        atomicAdd(&pk[dl], add);
    }
    __syncthreads();
    int c = 0;
    if (t < 256) { c = (int)(pk[t] >> 40); sh[t] = c; }
    __syncthreads();
    for (int off = 1; off < 256; off <<= 1) {
        int a = (t < 256 && t >= off) ? sh[t - off] : 0;
        __syncthreads();
        if (t < 256) sh[t] += a;
        __syncthreads();
    }
    if (t < 256) {
        int gstart = r0 + sh[t] - c;
        cursor[t] = gstart;
        int node = k * 256 + t;
        if (node < NN) {
            float wsum = (float)(pk[t] & 0xFFFFFFFFFFULL) * (1.0f / 16777216.0f);
            float di = rsqrtf(wsum);
            row_ptr[node] = gstart;
            dinv[node] = di;
            if (node == NN - 1) row_ptr[NN] = EE;
#pragma unroll
            for (int f = 0; f < FINN; ++f)
                vfs[node * FINN + f] = vf[node * FINN + f] * di;
        }
    }
    __syncthreads();
    for (int e = r0 + t; e < r1; e += 1024) {
        int2 p = ebuk[e];
        int dl = (p.x >> 17) & 255;
        int pos = atomicAdd(&cursor[dl], 1);
        int2 q;
        q.x = (p.x & 0x1FFFF) << 7;  // src * 128 bytes
        q.y = p.y;
        epack[pos] = q;
    }
}

// layer-1 aggregation: acc6[i] = dinv[i] * (vfs[i] + sum w * vfs[s])
__global__ void k_gather6(const float* __restrict__ vfs, const float* __restrict__ dinv,
                          const int* __restrict__ rp, const int2* __restrict__ epack,
                          float* __restrict__ acc6) {
    int i = blockIdx.x * 256 + threadIdx.x;
    if (i >= NN) return;
    float av[FINN];
#pragma unroll
    for (int f = 0; f < FINN; ++f) av[f] = vfs[i * FINN + f];
    int e1 = rp[i + 1];
    for (int e = rp[i]; e < e1; ++e) {
        int2 p = epack[e];
        int s = p.x >> 7;
        float wn = __int_as_float(p.y);
#pragma unroll
        for (int f = 0; f < FINN; ++f) av[f] += vfs[s * FINN + f] * wn;
    }
    float di = dinv[i];
#pragma unroll
    for (int f = 0; f < FINN; ++f) acc6[i * FINN + f] = av[f] * di;
}

// Fused 64-dim layer (round-10 structure): wave per node, 8 nodes/block.
// 64-edge chunks staged to wave-private LDS; pair loop: half-wave hf takes
// even/odd edges, lane covers half2 fp; unroll 8 pairs, two independent
// accumulator pairs to shorten the fmaf chain. epack.x pre-scaled byte offset.
// Epilogue: in-LDS 64->64 GEMM + bias + sigmoid; HEAD fuses the 64->5 head.
template <bool HEAD>
__global__ __launch_bounds__(512) void k_layer64f(
    const __half* __restrict__ yin, const float* __restrict__ dinv,
    const int* __restrict__ rp, const int2* __restrict__ epack,
    const float* __restrict__ W, const float* __restrict__ b,
    __half* __restrict__ yout,
    const float* __restrict__ Wl, const float* __restrict__ bl,
    float* __restrict__ outp) {
    __shared__ float Wsh[HH * HH];   // 16 KB
    __shared__ float bsh[HH];
    __shared__ float aggsh[8 * HH];
    __shared__ float Wlsh[HH * FOUT];
    __shared__ float blsh[FOUT];
    __shared__ int2 estage[8 * 64];  // 512 B wave-private edge staging per wave
    for (int t = threadIdx.x; t < HH * HH; t += 512) Wsh[t] = W[t];
    if (threadIdx.x < HH) bsh[threadIdx.x] = b[threadIdx.x];
    if (HEAD) {
        for (int t = threadIdx.x; t < HH * FOUT; t += 512) Wlsh[t] = Wl[t];
        if (threadIdx.x < FOUT) blsh[threadIdx.x] = bl[threadIdx.x];
    }

    int wv = threadIdx.x >> 6, lane = threadIdx.x & 63;
    int i = blockIdx.x * 8 + wv;  // grids divide exactly: no partial blocks
    int hf = lane >> 5, fp = lane & 31;
    unsigned fp4 = (unsigned)fp * 4u;
    float di = dinv[i];
    const char* ybp = (const char*)yin;
    float ax0 = 0.0f, ay0 = 0.0f, ax1 = 0.0f, ay1 = 0.0f;
    if (hf == 0) {  // self loop (coeff 1), even half only
        unsigned vpk = *(const unsigned*)(ybp + (size_t)i * 128 + fp4);
        __half2 h = *(__half2*)&vpk;
        ax0 = __half2float(h.x);
        ay0 = __half2float(h.y);
    }
    int e0 = __builtin_amdgcn_readfirstlane(rp[i]);
    int e1 = __builtin_amdgcn_readfirstlane(rp[i + 1]);
    int2* sw = &estage[wv * 64];
    for (int base = e0; base < e1; base += 64) {
        int n = e1 - base;
        if (n > 64) n = 64;
        if (lane < n) sw[lane] = epack[base + lane];  // coalesced 512B/wave
        int n2 = n & ~1;
        int j = 0;
        for (; j + 16 <= n2; j += 16) {  // 8 pairs = 16 rows in flight
            int2 r0 = sw[j + 0 + hf],  r1 = sw[j + 2 + hf];
            int2 r2 = sw[j + 4 + hf],  r3 = sw[j + 6 + hf];
            int2 r4 = sw[j + 8 + hf],  r5 = sw[j + 10 + hf];
            int2 r6 = sw[j + 12 + hf], r7 = sw[j + 14 + hf];
            unsigned v0 = *(const unsigned*)(ybp + ((unsigned)r0.x + fp4));
            unsigned v1 = *(const unsigned*)(ybp + ((unsigned)r1.x + fp4));
            unsigned v2 = *(const unsigned*)(ybp + ((unsigned)r2.x + fp4));
            unsigned v3 = *(const unsigned*)(ybp + ((unsigned)r3.x + fp4));
            unsigned v4 = *(const unsigned*)(ybp + ((unsigned)r4.x + fp4));
            unsigned v5 = *(const unsigned*)(ybp + ((unsigned)r5.x + fp4));
            unsigned v6 = *(const unsigned*)(ybp + ((unsigned)r6.x + fp4));
            unsigned v7 = *(const unsigned*)(ybp + ((unsigned)r7.x + fp4));
            __half2 h0 = *(__half2*)&v0, h1 = *(__half2*)&v1;
            __half2 h2 = *(__half2*)&v2, h3 = *(__half2*)&v3;
            __half2 h4 = *(__half2*)&v4, h5 = *(__half2*)&v5;
            __half2 h6 = *(__half2*)&v6, h7 = *(__half2*)&v7;
            float w0 = __int_as_float(r0.y), w1 = __int_as_float(r1.y);
            float w2 = __int_as_float(r2.y), w3 = __int_as_float(r3.y);
            float w4 = __int_as_float(r4.y), w5 = __int_as_float(r5.y);
            float w6 = __int_as_float(r6.y), w7 = __int_as_float(r7.y);
            ax0 = fmaf(__half2float(h0.x), w0, ax0);
            ay0 = fmaf(__half2float(h0.y), w0, ay0);
            ax1 = fmaf(__half2float(h1.x), w1, ax1);
            ay1 = fmaf(__half2float(h1.y), w1, ay1);
            ax0 = fmaf(__half2float(h2.x), w2, ax0);
            ay0 = fmaf(__half2float(h2.y), w2, ay0);
            ax1 = fmaf(__half2float(h3.x), w3, ax1);
            ay1 = fmaf(__half2float(h3.y), w3, ay1);
            ax0 = fmaf(__half2float(h4.x), w4, ax0);
            ay0 = fmaf(__half2float(h4.y), w4, ay0);
            ax1 = fmaf(__half2float(h5.x), w5, ax1);
            ay1 = fmaf(__half2float(h5.y), w5, ay1);
            ax0 = fmaf(__half2float(h6.x), w6, ax0);
            ay0 = fmaf(__half2float(h6.y), w6, ay0);
            ax1 = fmaf(__half2float(h7.x), w7, ax1);
            ay1 = fmaf(__half2float(h7.y), w7, ay1);
        }
        for (; j + 8 <= n2; j += 8) {  // 4 pairs
            int2 r0 = sw[j + 0 + hf], r1 = sw[j + 2 + hf];
            int2 r2 = sw[j + 4 + hf], r3 = sw[j + 6 + hf];
            unsigned v0 = *(const unsigned*)(ybp + ((unsigned)r0.x + fp4));
            unsigned v1 = *(const unsigned*)(ybp + ((unsigned)r1.x + fp4));
            unsigned v2 = *(const unsigned*)(ybp + ((unsigned)r2.x + fp4));
            unsigned v3 = *(const unsigned*)(ybp + ((unsigned)r3.x + fp4));
            __half2 h0 = *(__half2*)&v0, h1 = *(__half2*)&v1;
            __half2 h2 = *(__half2*)&v2, h3 = *(__half2*)&v3;
            float w0 = __int_as_float(r0.y), w1 = __int_as_float(r1.y);
            float w2 = __int_as_float(r2.y), w3 = __int_as_float(r3.y);
            ax0 = fmaf(__half2float(h0.x), w0, ax0);
            ay0 = fmaf(__half2float(h0.y), w0, ay0);
            ax1 = fmaf(__half2float(h1.x), w1, ax1);
            ay1 = fmaf(__half2float(h1.y), w1, ay1);
            ax0 = fmaf(__half2float(h2.x), w2, ax0);
            ay0 = fmaf(__half2float(h2.y), w2, ay0);
            ax1 = fmaf(__half2float(h3.x), w3, ax1);
            ay1 = fmaf(__half2float(h3.y), w3, ay1);
        }
        for (; j < n2; j += 2) {
            int2 r = sw[j + hf];
            unsigned v = *(const unsigned*)(ybp + ((unsigned)r.x + fp4));
            float wn = __int_as_float(r.y);
            __half2 h = *(__half2*)&v;
            ax0 = fmaf(__half2float(h.x), wn, ax0);
            ay0 = fmaf(__half2float(h.y), wn, ay0);
        }
        if (n2 < n && hf == 0) {  // odd tail edge: even half takes it
            int2 r = sw[n2];
            unsigned v = *(const unsigned*)(ybp + ((unsigned)r.x + fp4));
            float wn = __int_as_float(r.y);
            __half2 h = *(__half2*)&v;
            ax0 = fmaf(__half2float(h.x), wn, ax0);
            ay0 = fmaf(__half2float(h.y), wn, ay0);
        }
    }
    float ax = ax0 + ax1, ay = ay0 + ay1;
    ax += __shfl(ax, lane ^ 32, 64);
    ay += __shfl(ay, lane ^ 32, 64);
    __syncthreads();  // Wsh/bsh staged
    if (hf == 0)
        ((float2*)&aggsh[wv * HH])[fp] = make_float2(ax * di, ay * di);
    __syncthreads();
    float o = bsh[lane];
    const float4* a4 = (const float4*)&aggsh[wv * HH];
#pragma unroll
    for (int f0 = 0; f0 < HH; f0 += 4) {
        float4 av = a4[f0 >> 2];  // broadcast read
        o += av.x * Wsh[(f0 + 0) * HH + lane];
        o += av.y * Wsh[(f0 + 1) * HH + lane];
        o += av.z * Wsh[(f0 + 2) * HH + lane];
        o += av.w * Wsh[(f0 + 3) * HH + lane];
    }
    float sig = 1.0f / (1.0f + __expf(-o));
    if (!HEAD) {
        yout[(size_t)i * HH + lane] = __float2half(sig * di);  // scaled y
    } else {
        aggsh[wv * HH + lane] = sig;  // unscaled, own-wave slice only
        __syncthreads();
        if (lane < FOUT) {
            float s = blsh[lane];
            const float* ar = &aggsh[wv * HH];
#pragma unroll
            for (int f = 0; f < HH; ++f) s += ar[f] * Wlsh[f * FOUT + lane];
            outp[(size_t)i * FOUT + lane] = s;
        }
    }
}

// out[i,:] = sigmoid(acc6[i,:FI] @ W + b) * dinv  (layer 1 only)
template <int FI>
__global__ void k_gemm_sig(const float* __restrict__ x, const float* __restrict__ W,
                           const float* __restrict__ b, const float* __restrict__ dinv,
                           __half* __restrict__ out) {
    __shared__ float Wsl[FI * 64];
    __shared__ float bsl[64];
    for (int t = threadIdx.x; t < FI * 64; t += 256) Wsl[t] = W[t];
    if (threadIdx.x < 64) bsl[threadIdx.x] = b[threadIdx.x];
    __syncthreads();
    int wave = (blockIdx.x * 256 + threadIdx.x) >> 6;
    int lane = threadIdx.x & 63;
    if (wave >= NN) return;
    const float* xr = x + (size_t)wave * FI;
    float s = bsl[lane];
#pragma unroll
    for (int f = 0; f < FI; ++f) s += xr[f] * Wsl[f * 64 + lane];
    float sig = 1.0f / (1.0f + __expf(-s));
    sig *= dinv[wave];
    out[(size_t)wave * HH + lane] = __float2half(sig);
}

extern "C" void kernel_launch(void* const* d_in, const int* in_sizes, int n_in,
                              void* d_out, int out_size, void* d_ws, size_t ws_size,
                              hipStream_t stream) {
    (void)in_sizes; (void)n_in; (void)out_size; (void)ws_size;
    const float* vf = (const float*)d_in[0];
    const int* edges = (const int*)d_in[1];
    const float* w = (const float*)d_in[2];
    const float* W1 = (const float*)d_in[3];
    const float* b1 = (const float*)d_in[4];
    const float* W2 = (const float*)d_in[5];
    const float* b2 = (const float*)d_in[6];
    const float* W3 = (const float*)d_in[7];
    const float* b3 = (const float*)d_in[8];
    const float* W4 = (const float*)d_in[9];
    const float* b4 = (const float*)d_in[10];
    const float* Wl = (const float*)d_in[11];
    const float* bl = (const float*)d_in[12];
    float* out = (float*)d_out;

    const int* src = edges;
    const int* dst = edges + EE;

    // workspace: 256B-aligned regions
    char* base = (char*)d_ws;
    size_t off = 0;
    float* dinv = (float*)(base + off);      off = alignup(off + sizeof(float) * NN);
    int* row_ptr = (int*)(base + off);       off = alignup(off + sizeof(int) * (NN + 1));
    int* bucket_ptr = (int*)(base + off);    off = alignup(off + sizeof(int) * (NBUK + 1));
    int* blockhist = (int*)(base + off);     off = alignup(off + sizeof(int) * NBH * NBUK);
    int2* ebuk = (int2*)(base + off);        off = alignup(off + sizeof(int2) * EE);
    int2* epack = (int2*)(base + off);       off = alignup(off + sizeof(int2) * EE);
    float* acc6 = (float*)(base + off);      off = alignup(off + sizeof(float) * (size_t)NN * FINN);
    float* vfs = (float*)(base + off);       off = alignup(off + sizeof(float) * (size_t)NN * FINN);
    __half* ya = (__half*)(base + off);      off = alignup(off + sizeof(__half) * (size_t)NN * HH);
    __half* yb = (__half*)(base + off);      off = alignup(off + sizeof(__half) * (size_t)NN * HH);

    // CSR build via two-level bucket sort (no global atomics); csrD also emits vfs
    k_histA<<<NBH, 1024, 0, stream>>>(dst, blockhist);
    k_scanB<<<1, 512, 0, stream>>>(blockhist, bucket_ptr);
    k_scatC<<<NBH, 1024, 0, stream>>>(src, dst, w, blockhist, ebuk);
    k_csrD<<<NBUK, 1024, 0, stream>>>(ebuk, bucket_ptr, row_ptr, dinv, epack, vf, vfs);

    // layer 1: gather(6) -> gemm+sigmoid (scaled -> ya)
    k_gather6<<<cdiv(NN, 256), 256, 0, stream>>>(vfs, dinv, row_ptr, epack, acc6);
    k_gemm_sig<FINN><<<cdiv(NN * 64, 256), 256, 0, stream>>>(acc6, W1, b1, dinv, ya);

    // layers 2,3 fused (scaled), ping-pong; layer 4 fused + head, 50k nodes only
    k_layer64f<false><<<NN / 8, 512, 0, stream>>>(ya, dinv, row_ptr, epack, W2, b2, yb,
                                                  nullptr, nullptr, nullptr);
    k_layer64f<false><<<NN / 8, 512, 0, stream>>>(yb, dinv, row_ptr, epack, W3, b3, ya,
                                                  nullptr, nullptr, nullptr);
    k_layer64f<true><<<NGNB / 8, 512, 0, stream>>>(ya, dinv, row_ptr, epack, W4, b4, nullptr,
                                                   Wl, bl, out);
}

// Round 13
// 459.735 us; speedup vs baseline: 1.0893x; 1.0207x over previous
//
#include <hip/hip_runtime.h>
#include <hip/hip_fp16.h>

#define NN 100000
#define EE 3200000
#define HH 64
#define FINN 6
#define FOUT 5
#define NGNB 50000
#define NBUK 391   // buckets of 256 nodes: bucket = dst >> 8
#define NBH 256    // blocks for hist/scatter passes (1 block/CU)

static inline int cdiv(int a, int b) { return (a + b - 1) / b; }
static inline size_t alignup(size_t x) { return (x + 255) & ~(size_t)255; }

// Pass A: per-block bucket histogram (LDS), write blockhist[block][NBUK]
__global__ __launch_bounds__(1024) void k_histA(const int* __restrict__ dst,
                                                int* __restrict__ blockhist) {
    __shared__ int hist[NBUK];
    int t = threadIdx.x;
    if (t < NBUK) hist[t] = 0;
    __syncthreads();
    for (int e = blockIdx.x * 1024 + t; e < EE; e += NBH * 1024)
        atomicAdd(&hist[dst[e] >> 8], 1);
    __syncthreads();
    if (t < NBUK) blockhist[blockIdx.x * NBUK + t] = hist[t];
}

// Pass B: turn blockhist into per-(block,bucket) bases; bucket_ptr = bucket starts
__global__ void k_scanB(int* __restrict__ blockhist, int* __restrict__ bucket_ptr) {
    __shared__ int sh[512];
    int t = threadIdx.x;
    int total = 0;
    if (t < NBUK)
        for (int b = 0; b < NBH; ++b) total += blockhist[b * NBUK + t];
    sh[t] = (t < NBUK) ? total : 0;
    __syncthreads();
    for (int off = 1; off < 512; off <<= 1) {
        int a = (t >= off) ? sh[t - off] : 0;
        __syncthreads();
        sh[t] += a;
        __syncthreads();
    }
    if (t < NBUK) {
        int base = sh[t] - total;  // exclusive
        bucket_ptr[t] = base;
        if (t == 0) bucket_ptr[NBUK] = EE;
        int run = base;
        for (int b = 0; b < NBH; ++b) {
            int c = blockhist[b * NBUK + t];
            blockhist[b * NBUK + t] = run;
            run += c;
        }
    }
}

// Pass C: scatter edges into bucket-grouped ebuk = {(dl<<17)|src, w}
__global__ __launch_bounds__(1024) void k_scatC(const int* __restrict__ src,
                                                const int* __restrict__ dst,
                                                const float* __restrict__ w,
                                                const int* __restrict__ blockhist,
                                                int2* __restrict__ ebuk) {
    __shared__ int cur[NBUK];
    int t = threadIdx.x;
    if (t < NBUK) cur[t] = blockhist[blockIdx.x * NBUK + t];
    __syncthreads();
    for (int e = blockIdx.x * 1024 + t; e < EE; e += NBH * 1024) {
        int d = dst[e];
        int k = d >> 8, dl = d & 255;
        int pos = atomicAdd(&cur[k], 1);
        int2 p;
        p.x = (dl << 17) | src[e];
        p.y = __float_as_int(w[e]);
        ebuk[pos] = p;
    }
}

// Pass D: per-bucket — one u64 LDS atomic per edge packs {count<<40, wsum fixed
// 2^-24}; scan; CSR scatter. epack.x = src*128 (fp16-row byte offset).
// Tail: computes vfs = vf * dinv for this bucket's 256 nodes (fused k_vfs).
__global__ __launch_bounds__(1024) void k_csrD(const int2* __restrict__ ebuk,
                                               const int* __restrict__ bucket_ptr,
                                               int* __restrict__ row_ptr,
                                               float* __restrict__ dinv,
                                               int2* __restrict__ epack,
                                               const float* __restrict__ vf,
                                               float* __restrict__ vfs) {
    __shared__ unsigned long long pk[256];
    __shared__ int sh[256];
    __shared__ int cursor[256];
    int t = threadIdx.x;
    int k = blockIdx.x;
    if (t < 256) pk[t] = (1ULL << 24);  // self-loop weight 1.0 (fixed point), count 0
    __syncthreads();
    int r0 = bucket_ptr[k], r1 = bucket_ptr[k + 1];
    for (int e = r0 + t; e < r1; e += 1024) {
        int2 p = ebuk[e];
        int dl = (p.x >> 17) & 255;
        unsigned long long add =
            (1ULL << 40) |
            (unsigned long long)(__int_as_float(p.y) * 16777216.0f);
        atomicAdd(&pk[dl], add);
    }
    __syncthreads();
    int c = 0;
    if (t < 256) { c = (int)(pk[t] >> 40); sh[t] = c; }
    __syncthreads();
    for (int off = 1; off < 256; off <<= 1) {
        int a = (t < 256 && t >= off) ? sh[t - off] : 0;
        __syncthreads();
        if (t < 256) sh[t] += a;
        __syncthreads();
    }
    if (t < 256) {
        int gstart = r0 + sh[t] - c;
        cursor[t] = gstart;
        int node = k * 256 + t;
        if (node < NN) {
            float wsum = (float)(pk[t] & 0xFFFFFFFFFFULL) * (1.0f / 16777216.0f);
            float di = rsqrtf(wsum);
            row_ptr[node] = gstart;
            dinv[node] = di;
            if (node == NN - 1) row_ptr[NN] = EE;
#pragma unroll
            for (int f = 0; f < FINN; ++f)
                vfs[node * FINN + f] = vf[node * FINN + f] * di;
        }
    }
    __syncthreads();
    for (int e = r0 + t; e < r1; e += 1024) {
        int2 p = ebuk[e];
        int dl = (p.x >> 17) & 255;
        int pos = atomicAdd(&cursor[dl], 1);
        int2 q;
        q.x = (p.x & 0x1FFFF) << 7;  // src * 128 bytes
        q.y = p.y;
        epack[pos] = q;
    }
}

// layer-1 aggregation: acc6[i] = dinv[i] * (vfs[i] + sum w * vfs[s])
__global__ void k_gather6(const float* __restrict__ vfs, const float* __restrict__ dinv,
                          const int* __restrict__ rp, const int2* __restrict__ epack,
                          float* __restrict__ acc6) {
    int i = blockIdx.x * 256 + threadIdx.x;
    if (i >= NN) return;
    float av[FINN];
#pragma unroll
    for (int f = 0; f < FINN; ++f) av[f] = vfs[i * FINN + f];
    int e1 = rp[i + 1];
    for (int e = rp[i]; e < e1; ++e) {
        int2 p = epack[e];
        int s = p.x >> 7;
        float wn = __int_as_float(p.y);
#pragma unroll
        for (int f = 0; f < FINN; ++f) av[f] += vfs[s * FINN + f] * wn;
    }
    float di = dinv[i];
#pragma unroll
    for (int f = 0; f < FINN; ++f) acc6[i * FINN + f] = av[f] * di;
}

// Fused 64-dim layer: wave per node, 8 nodes/block. Barrier-decoupled: one
// __syncthreads after W staging; gather + epilogue are fully wave-independent
// (aggsh slices are wave-private), so a high-degree node never stalls the
// other 7 waves. Pair gather (round-10): half-wave hf takes even/odd edges,
// lane covers half2 fp; 8-pair unroll; epack.x pre-scaled byte offset;
// fma_mix accumulate. Epilogue: in-LDS 64->64 GEMM + bias + sigmoid; HEAD
// fuses the 64->5 head and writes out directly.
template <bool HEAD>
__global__ __launch_bounds__(512) void k_layer64f(
    const __half* __restrict__ yin, const float* __restrict__ dinv,
    const int* __restrict__ rp, const int2* __restrict__ epack,
    const float* __restrict__ W, const float* __restrict__ b,
    __half* __restrict__ yout,
    const float* __restrict__ Wl, const float* __restrict__ bl,
    float* __restrict__ outp) {
    __shared__ float Wsh[HH * HH];   // 16 KB
    __shared__ float bsh[HH];
    __shared__ float aggsh[8 * HH];
    __shared__ float Wlsh[HH * FOUT];
    __shared__ float blsh[FOUT];
    __shared__ int2 estage[8 * 64];  // 512 B wave-private edge staging per wave
    for (int t = threadIdx.x; t < HH * HH; t += 512) Wsh[t] = W[t];
    if (threadIdx.x < HH) bsh[threadIdx.x] = b[threadIdx.x];
    if (HEAD) {
        for (int t = threadIdx.x; t < HH * FOUT; t += 512) Wlsh[t] = Wl[t];
        if (threadIdx.x < FOUT) blsh[threadIdx.x] = bl[threadIdx.x];
    }
    __syncthreads();  // the ONLY barrier: Wsh/bsh(/Wlsh/blsh) staged

    int wv = threadIdx.x >> 6, lane = threadIdx.x & 63;
    int i = blockIdx.x * 8 + wv;  // grids divide exactly: no partial blocks
    int hf = lane >> 5, fp = lane & 31;
    unsigned fp4 = (unsigned)fp * 4u;
    float di = dinv[i];
    const char* ybp = (const char*)yin;
    float ax0 = 0.0f, ay0 = 0.0f, ax1 = 0.0f, ay1 = 0.0f;
    if (hf == 0) {  // self loop (coeff 1), even half only
        unsigned vpk = *(const unsigned*)(ybp + (size_t)i * 128 + fp4);
        __half2 h = *(__half2*)&vpk;
        ax0 = __half2float(h.x);
        ay0 = __half2float(h.y);
    }
    int e0 = __builtin_amdgcn_readfirstlane(rp[i]);
    int e1 = __builtin_amdgcn_readfirstlane(rp[i + 1]);
    int2* sw = &estage[wv * 64];
    for (int base = e0; base < e1; base += 64) {
        int n = e1 - base;
        if (n > 64) n = 64;
        if (lane < n) sw[lane] = epack[base + lane];  // coalesced 512B/wave
        int n2 = n & ~1;
        int j = 0;
        for (; j + 16 <= n2; j += 16) {  // 8 pairs = 16 rows in flight
            int2 r0 = sw[j + 0 + hf],  r1 = sw[j + 2 + hf];
            int2 r2 = sw[j + 4 + hf],  r3 = sw[j + 6 + hf];
            int2 r4 = sw[j + 8 + hf],  r5 = sw[j + 10 + hf];
            int2 r6 = sw[j + 12 + hf], r7 = sw[j + 14 + hf];
            unsigned v0 = *(const unsigned*)(ybp + ((unsigned)r0.x + fp4));
            unsigned v1 = *(const unsigned*)(ybp + ((unsigned)r1.x + fp4));
            unsigned v2 = *(const unsigned*)(ybp + ((unsigned)r2.x + fp4));
            unsigned v3 = *(const unsigned*)(ybp + ((unsigned)r3.x + fp4));
            unsigned v4 = *(const unsigned*)(ybp + ((unsigned)r4.x + fp4));
            unsigned v5 = *(const unsigned*)(ybp + ((unsigned)r5.x + fp4));
            unsigned v6 = *(const unsigned*)(ybp + ((unsigned)r6.x + fp4));
            unsigned v7 = *(const unsigned*)(ybp + ((unsigned)r7.x + fp4));
            __half2 h0 = *(__half2*)&v0, h1 = *(__half2*)&v1;
            __half2 h2 = *(__half2*)&v2, h3 = *(__half2*)&v3;
            __half2 h4 = *(__half2*)&v4, h5 = *(__half2*)&v5;
            __half2 h6 = *(__half2*)&v6, h7 = *(__half2*)&v7;
            float w0 = __int_as_float(r0.y), w1 = __int_as_float(r1.y);
            float w2 = __int_as_float(r2.y), w3 = __int_as_float(r3.y);
            float w4 = __int_as_float(r4.y), w5 = __int_as_float(r5.y);
            float w6 = __int_as_float(r6.y), w7 = __int_as_float(r7.y);
            ax0 = fmaf(__half2float(h0.x), w0, ax0);
            ay0 = fmaf(__half2float(h0.y), w0, ay0);
            ax1 = fmaf(__half2float(h1.x), w1, ax1);
            ay1 = fmaf(__half2float(h1.y), w1, ay1);
            ax0 = fmaf(__half2float(h2.x), w2, ax0);
            ay0 = fmaf(__half2float(h2.y), w2, ay0);
            ax1 = fmaf(__half2float(h3.x), w3, ax1);
            ay1 = fmaf(__half2float(h3.y), w3, ay1);
            ax0 = fmaf(__half2float(h4.x), w4, ax0);
            ay0 = fmaf(__half2float(h4.y), w4, ay0);
            ax1 = fmaf(__half2float(h5.x), w5, ax1);
            ay1 = fmaf(__half2float(h5.y), w5, ay1);
            ax0 = fmaf(__half2float(h6.x), w6, ax0);
            ay0 = fmaf(__half2float(h6.y), w6, ay0);
            ax1 = fmaf(__half2float(h7.x), w7, ax1);
            ay1 = fmaf(__half2float(h7.y), w7, ay1);
        }
        for (; j + 8 <= n2; j += 8) {  // 4 pairs
            int2 r0 = sw[j + 0 + hf], r1 = sw[j + 2 + hf];
            int2 r2 = sw[j + 4 + hf], r3 = sw[j + 6 + hf];
            unsigned v0 = *(const unsigned*)(ybp + ((unsigned)r0.x + fp4));
            unsigned v1 = *(const unsigned*)(ybp + ((unsigned)r1.x + fp4));
            unsigned v2 = *(const unsigned*)(ybp + ((unsigned)r2.x + fp4));
            unsigned v3 = *(const unsigned*)(ybp + ((unsigned)r3.x + fp4));
            __half2 h0 = *(__half2*)&v0, h1 = *(__half2*)&v1;
            __half2 h2 = *(__half2*)&v2, h3 = *(__half2*)&v3;
            float w0 = __int_as_float(r0.y), w1 = __int_as_float(r1.y);
            float w2 = __int_as_float(r2.y), w3 = __int_as_float(r3.y);
            ax0 = fmaf(__half2float(h0.x), w0, ax0);
            ay0 = fmaf(__half2float(h0.y), w0, ay0);
            ax1 = fmaf(__half2float(h1.x), w1, ax1);
            ay1 = fmaf(__half2float(h1.y), w1, ay1);
            ax0 = fmaf(__half2float(h2.x), w2, ax0);
            ay0 = fmaf(__half2float(h2.y), w2, ay0);
            ax1 = fmaf(__half2float(h3.x), w3, ax1);
            ay1 = fmaf(__half2float(h3.y), w3, ay1);
        }
        for (; j < n2; j += 2) {
            int2 r = sw[j + hf];
            unsigned v = *(const unsigned*)(ybp + ((unsigned)r.x + fp4));
            float wn = __int_as_float(r.y);
            __half2 h = *(__half2*)&v;
            ax0 = fmaf(__half2float(h.x), wn, ax0);
            ay0 = fmaf(__half2float(h.y), wn, ay0);
        }
        if (n2 < n && hf == 0) {  // odd tail edge: even half takes it
            int2 r = sw[n2];
            unsigned v = *(const unsigned*)(ybp + ((unsigned)r.x + fp4));
            float wn = __int_as_float(r.y);
            __half2 h = *(__half2*)&v;
            ax0 = fmaf(__half2float(h.x), wn, ax0);
            ay0 = fmaf(__half2float(h.y), wn, ay0);
        }
    }
    float ax = ax0 + ax1, ay = ay0 + ay1;
    ax += __shfl(ax, lane ^ 32, 64);
    ay += __shfl(ay, lane ^ 32, 64);
    // wave-private aggsh slice: no barrier needed (same-wave LDS ordering)
    if (hf == 0)
        ((float2*)&aggsh[wv * HH])[fp] = make_float2(ax * di, ay * di);
    float o = bsh[lane];
    const float4* a4 = (const float4*)&aggsh[wv * HH];
#pragma unroll
    for (int f0 = 0; f0 < HH; f0 += 4) {
        float4 av = a4[f0 >> 2];  // broadcast read, own-wave slice
        o += av.x * Wsh[(f0 + 0) * HH + lane];
        o += av.y * Wsh[(f0 + 1) * HH + lane];
        o += av.z * Wsh[(f0 + 2) * HH + lane];
        o += av.w * Wsh[(f0 + 3) * HH + lane];
    }
    float sig = 1.0f / (1.0f + __expf(-o));
    if (!HEAD) {
        yout[(size_t)i * HH + lane] = __float2half(sig * di);  // scaled y
    } else {
        aggsh[wv * HH + lane] = sig;  // own-wave slice, no barrier
        if (lane < FOUT) {
            float s = blsh[lane];
            const float* ar = &aggsh[wv * HH];
#pragma unroll
            for (int f = 0; f < HH; ++f) s += ar[f] * Wlsh[f * FOUT + lane];
            outp[(size_t)i * FOUT + lane] = s;
        }
    }
}

// out[i,:] = sigmoid(acc6[i,:FI] @ W + b) * dinv  (layer 1 only)
template <int FI>
__global__ void k_gemm_sig(const float* __restrict__ x, const float* __restrict__ W,
                           const float* __restrict__ b, const float* __restrict__ dinv,
                           __half* __restrict__ out) {
    __shared__ float Wsl[FI * 64];
    __shared__ float bsl[64];
    for (int t = threadIdx.x; t < FI * 64; t += 256) Wsl[t] = W[t];
    if (threadIdx.x < 64) bsl[threadIdx.x] = b[threadIdx.x];
    __syncthreads();
    int wave = (blockIdx.x * 256 + threadIdx.x) >> 6;
    int lane = threadIdx.x & 63;
    if (wave >= NN) return;
    const float* xr = x + (size_t)wave * FI;
    float s = bsl[lane];
#pragma unroll
    for (int f = 0; f < FI; ++f) s += xr[f] * Wsl[f * 64 + lane];
    float sig = 1.0f / (1.0f + __expf(-s));
    sig *= dinv[wave];
    out[(size_t)wave * HH + lane] = __float2half(sig);
}

extern "C" void kernel_launch(void* const* d_in, const int* in_sizes, int n_in,
                              void* d_out, int out_size, void* d_ws, size_t ws_size,
                              hipStream_t stream) {
    (void)in_sizes; (void)n_in; (void)out_size; (void)ws_size;
    const float* vf = (const float*)d_in[0];
    const int* edges = (const int*)d_in[1];
    const float* w = (const float*)d_in[2];
    const float* W1 = (const float*)d_in[3];
    const float* b1 = (const float*)d_in[4];
    const float* W2 = (const float*)d_in[5];
    const float* b2 = (const float*)d_in[6];
    const float* W3 = (const float*)d_in[7];
    const float* b3 = (const float*)d_in[8];
    const float* W4 = (const float*)d_in[9];
    const float* b4 = (const float*)d_in[10];
    const float* Wl = (const float*)d_in[11];
    const float* bl = (const float*)d_in[12];
    float* out = (float*)d_out;

    const int* src = edges;
    const int* dst = edges + EE;

    // workspace: 256B-aligned regions
    char* base = (char*)d_ws;
    size_t off = 0;
    float* dinv = (float*)(base + off);      off = alignup(off + sizeof(float) * NN);
    int* row_ptr = (int*)(base + off);       off = alignup(off + sizeof(int) * (NN + 1));
    int* bucket_ptr = (int*)(base + off);    off = alignup(off + sizeof(int) * (NBUK + 1));
    int* blockhist = (int*)(base + off);     off = alignup(off + sizeof(int) * NBH * NBUK);
    int2* ebuk = (int2*)(base + off);        off = alignup(off + sizeof(int2) * EE);
    int2* epack = (int2*)(base + off);       off = alignup(off + sizeof(int2) * EE);
    float* acc6 = (float*)(base + off);      off = alignup(off + sizeof(float) * (size_t)NN * FINN);
    float* vfs = (float*)(base + off);       off = alignup(off + sizeof(float) * (size_t)NN * FINN);
    __half* ya = (__half*)(base + off);      off = alignup(off + sizeof(__half) * (size_t)NN * HH);
    __half* yb = (__half*)(base + off);      off = alignup(off + sizeof(__half) * (size_t)NN * HH);

    // CSR build via two-level bucket sort (no global atomics); csrD also emits vfs
    k_histA<<<NBH, 1024, 0, stream>>>(dst, blockhist);
    k_scanB<<<1, 512, 0, stream>>>(blockhist, bucket_ptr);
    k_scatC<<<NBH, 1024, 0, stream>>>(src, dst, w, blockhist, ebuk);
    k_csrD<<<NBUK, 1024, 0, stream>>>(ebuk, bucket_ptr, row_ptr, dinv, epack, vf, vfs);

    // layer 1: gather(6) -> gemm+sigmoid (scaled -> ya)
    k_gather6<<<cdiv(NN, 256), 256, 0, stream>>>(vfs, dinv, row_ptr, epack, acc6);
    k_gemm_sig<FINN><<<cdiv(NN * 64, 256), 256, 0, stream>>>(acc6, W1, b1, dinv, ya);

    // layers 2,3 fused (scaled), ping-pong; layer 4 fused + head, 50k nodes only
    k_layer64f<false><<<NN / 8, 512, 0, stream>>>(ya, dinv, row_ptr, epack, W2, b2, yb,
                                                  nullptr, nullptr, nullptr);
    k_layer64f<false><<<NN / 8, 512, 0, stream>>>(yb, dinv, row_ptr, epack, W3, b3, ya,
                                                  nullptr, nullptr, nullptr);
    k_layer64f<true><<<NGNB / 8, 512, 0, stream>>>(ya, dinv, row_ptr, epack, W4, b4, nullptr,
                                                   Wl, bl, out);
}

// Round 14
// 413.035 us; speedup vs baseline: 1.2125x; 1.1131x over previous
//
#include <hip/hip_runtime.h>
#include <hip/hip_fp16.h>

#define NN 100000
#define EE 3200000
#define HH 64
#define FINN 6
#define FOUT 5
#define NGNB 50000
#define NBUK 391   // buckets of 256 nodes: bucket = dst >> 8
#define NBH 256    // blocks for hist/scatter passes (1 block/CU)

static inline int cdiv(int a, int b) { return (a + b - 1) / b; }
static inline size_t alignup(size_t x) { return (x + 255) & ~(size_t)255; }

// Pass A: per-block bucket histogram (LDS), write blockhist[block][NBUK]
__global__ __launch_bounds__(1024) void k_histA(const int* __restrict__ dst,
                                                int* __restrict__ blockhist) {
    __shared__ int hist[NBUK];
    int t = threadIdx.x;
    if (t < NBUK) hist[t] = 0;
    __syncthreads();
    for (int e = blockIdx.x * 1024 + t; e < EE; e += NBH * 1024)
        atomicAdd(&hist[dst[e] >> 8], 1);
    __syncthreads();
    if (t < NBUK) blockhist[blockIdx.x * NBUK + t] = hist[t];
}

// Pass B: turn blockhist into per-(block,bucket) bases; bucket_ptr = bucket starts
__global__ void k_scanB(int* __restrict__ blockhist, int* __restrict__ bucket_ptr) {
    __shared__ int sh[512];
    int t = threadIdx.x;
    int total = 0;
    if (t < NBUK)
        for (int b = 0; b < NBH; ++b) total += blockhist[b * NBUK + t];
    sh[t] = (t < NBUK) ? total : 0;
    __syncthreads();
    for (int off = 1; off < 512; off <<= 1) {
        int a = (t >= off) ? sh[t - off] : 0;
        __syncthreads();
        sh[t] += a;
        __syncthreads();
    }
    if (t < NBUK) {
        int base = sh[t] - total;  // exclusive
        bucket_ptr[t] = base;
        if (t == 0) bucket_ptr[NBUK] = EE;
        int run = base;
        for (int b = 0; b < NBH; ++b) {
            int c = blockhist[b * NBUK + t];
            blockhist[b * NBUK + t] = run;
            run += c;
        }
    }
}

// Pass C: scatter edges into bucket-grouped ebuk = {(dl<<17)|src, w}
__global__ __launch_bounds__(1024) void k_scatC(const int* __restrict__ src,
                                                const int* __restrict__ dst,
                                                const float* __restrict__ w,
                                                const int* __restrict__ blockhist,
                                                int2* __restrict__ ebuk) {
    __shared__ int cur[NBUK];
    int t = threadIdx.x;
    if (t < NBUK) cur[t] = blockhist[blockIdx.x * NBUK + t];
    __syncthreads();
    for (int e = blockIdx.x * 1024 + t; e < EE; e += NBH * 1024) {
        int d = dst[e];
        int k = d >> 8, dl = d & 255;
        int pos = atomicAdd(&cur[k], 1);
        int2 p;
        p.x = (dl << 17) | src[e];
        p.y = __float_as_int(w[e]);
        ebuk[pos] = p;
    }
}

// Pass D: per-bucket — one u64 LDS atomic per edge packs {count<<40, wsum fixed
// 2^-24}; scan; CSR scatter. epack.x = src*128 (fp16-row byte offset).
// Tail: computes vfs = vf * dinv for this bucket's 256 nodes.
__global__ __launch_bounds__(1024) void k_csrD(const int2* __restrict__ ebuk,
                                               const int* __restrict__ bucket_ptr,
                                               int* __restrict__ row_ptr,
                                               float* __restrict__ dinv,
                                               int2* __restrict__ epack,
                                               const float* __restrict__ vf,
                                               float* __restrict__ vfs) {
    __shared__ unsigned long long pk[256];
    __shared__ int sh[256];
    __shared__ int cursor[256];
    int t = threadIdx.x;
    int k = blockIdx.x;
    if (t < 256) pk[t] = (1ULL << 24);  // self-loop weight 1.0 (fixed point), count 0
    __syncthreads();
    int r0 = bucket_ptr[k], r1 = bucket_ptr[k + 1];
    for (int e = r0 + t; e < r1; e += 1024) {
        int2 p = ebuk[e];
        int dl = (p.x >> 17) & 255;
        unsigned long long add =
            (1ULL << 40) |
            (unsigned long long)(__int_as_float(p.y) * 16777216.0f);
        atomicAdd(&pk[dl], add);
    }
    __syncthreads();
    int c = 0;
    if (t < 256) { c = (int)(pk[t] >> 40); sh[t] = c; }
    __syncthreads();
    for (int off = 1; off < 256; off <<= 1) {
        int a = (t < 256 && t >= off) ? sh[t - off] : 0;
        __syncthreads();
        if (t < 256) sh[t] += a;
        __syncthreads();
    }
    if (t < 256) {
        int gstart = r0 + sh[t] - c;
        cursor[t] = gstart;
        int node = k * 256 + t;
        if (node < NN) {
            float wsum = (float)(pk[t] & 0xFFFFFFFFFFULL) * (1.0f / 16777216.0f);
            float di = rsqrtf(wsum);
            row_ptr[node] = gstart;
            dinv[node] = di;
            if (node == NN - 1) row_ptr[NN] = EE;
#pragma unroll
            for (int f = 0; f < FINN; ++f)
                vfs[node * FINN + f] = vf[node * FINN + f] * di;
        }
    }
    __syncthreads();
    for (int e = r0 + t; e < r1; e += 1024) {
        int2 p = ebuk[e];
        int dl = (p.x >> 17) & 255;
        int pos = atomicAdd(&cursor[dl], 1);
        int2 q;
        q.x = (p.x & 0x1FFFF) << 7;  // src * 128 bytes
        q.y = p.y;
        epack[pos] = q;
    }
}

// Fused layer 1: half-wave (32 lanes) per node, lane-per-edge gather of the
// 6-dim vfs rows (32 rows in flight), shfl-tree reduce, then 6->64 GEMM +
// bias + sigmoid (scaled by dinv) in-kernel. Wave handles 2 nodes.
__global__ __launch_bounds__(512) void k_layer1f(
    const float* __restrict__ vfs, const float* __restrict__ dinv,
    const int* __restrict__ rp, const int2* __restrict__ epack,
    const float* __restrict__ W1, const float* __restrict__ b1,
    __half* __restrict__ ya) {
    __shared__ float Wsh[FINN * HH];
    __shared__ float bsh[HH];
    __shared__ float avsh[8][2][FINN];
    int t = threadIdx.x;
    if (t < FINN * HH) Wsh[t] = W1[t];
    if (t < HH) bsh[t] = b1[t];
    __syncthreads();
    int wv = t >> 6, lane = t & 63;
    int half = lane >> 5, hl = lane & 31;
    int i = blockIdx.x * 16 + wv * 2 + half;  // node for this half-wave
    float av0 = 0.0f, av1 = 0.0f, av2 = 0.0f, av3 = 0.0f, av4 = 0.0f, av5 = 0.0f;
    if (i < NN) {
        int e0 = rp[i], e1 = rp[i + 1];
        for (int e = e0 + hl; e < e1; e += 32) {
            int2 p = epack[e];
            int s = p.x >> 7;  // epack.x = src*128
            float wn = __int_as_float(p.y);
            const float2* row = (const float2*)(vfs + (size_t)s * FINN);
            float2 r0 = row[0], r1 = row[1], r2 = row[2];
            av0 = fmaf(r0.x, wn, av0);
            av1 = fmaf(r0.y, wn, av1);
            av2 = fmaf(r1.x, wn, av2);
            av3 = fmaf(r1.y, wn, av3);
            av4 = fmaf(r2.x, wn, av4);
            av5 = fmaf(r2.y, wn, av5);
        }
    }
    // reduce across the 32 lanes of this half (xor tree stays within half)
#pragma unroll
    for (int m = 1; m < 32; m <<= 1) {
        av0 += __shfl(av0, lane ^ m, 64);
        av1 += __shfl(av1, lane ^ m, 64);
        av2 += __shfl(av2, lane ^ m, 64);
        av3 += __shfl(av3, lane ^ m, 64);
        av4 += __shfl(av4, lane ^ m, 64);
        av5 += __shfl(av5, lane ^ m, 64);
    }
    if (i < NN && hl == 0) {  // add self term, scale by dinv, stash (wave-private)
        float di = dinv[i];
        const float2* srow = (const float2*)(vfs + (size_t)i * FINN);
        float2 s0 = srow[0], s1 = srow[1], s2 = srow[2];
        avsh[wv][half][0] = (s0.x + av0) * di;
        avsh[wv][half][1] = (s0.y + av1) * di;
        avsh[wv][half][2] = (s1.x + av2) * di;
        avsh[wv][half][3] = (s1.y + av3) * di;
        avsh[wv][half][4] = (s2.x + av4) * di;
        avsh[wv][half][5] = (s2.y + av5) * di;
    }
    // epilogue: all 64 lanes compute each of the wave's 2 nodes (same-wave LDS)
#pragma unroll
    for (int nb = 0; nb < 2; ++nb) {
        int node = blockIdx.x * 16 + wv * 2 + nb;
        if (node < NN) {
            float s = bsh[lane];
#pragma unroll
            for (int f = 0; f < FINN; ++f)
                s += avsh[wv][nb][f] * Wsh[f * HH + lane];
            float sig = 1.0f / (1.0f + __expf(-s));
            sig *= dinv[node];
            ya[(size_t)node * HH + lane] = __float2half(sig);
        }
    }
}

// Fused 64-dim layer: wave per K=4 consecutive nodes, 8 waves/block.
// Software-pipelined edge records: node k+1's first chunk is register-
// prefetched during node k's gather and ds_written into a ping-pong LDS
// buffer after k's epilogue — the per-node record-load stall is paid once
// per 4 nodes. Pair gather: half-wave hf takes even/odd edges, lane covers
// half2 fp; 8-pair unroll; epack.x pre-scaled byte offset; fma_mix.
// Epilogue: in-LDS 64->64 GEMM + bias + sigmoid; HEAD fuses the 64->5 head.
template <bool HEAD>
__global__ __launch_bounds__(512) void k_layer64f(
    const __half* __restrict__ yin, const float* __restrict__ dinv,
    const int* __restrict__ rp, const int2* __restrict__ epack,
    const float* __restrict__ W, const float* __restrict__ b,
    __half* __restrict__ yout,
    const float* __restrict__ Wl, const float* __restrict__ bl,
    float* __restrict__ outp) {
    const int K = 4;
    const int nlim = HEAD ? NGNB : NN;
    __shared__ float Wsh[HH * HH];   // 16 KB
    __shared__ float bsh[HH];
    __shared__ float aggsh[8 * HH];
    __shared__ float Wlsh[HH * FOUT];
    __shared__ float blsh[FOUT];
    __shared__ int2 estage[8][2][64];  // ping-pong edge staging per wave (8 KB)
    for (int t = threadIdx.x; t < HH * HH; t += 512) Wsh[t] = W[t];
    if (threadIdx.x < HH) bsh[threadIdx.x] = b[threadIdx.x];
    if (HEAD) {
        for (int t = threadIdx.x; t < HH * FOUT; t += 512) Wlsh[t] = Wl[t];
        if (threadIdx.x < FOUT) blsh[threadIdx.x] = bl[threadIdx.x];
    }
    __syncthreads();  // the ONLY barrier: Wsh/bsh(/Wlsh/blsh) staged

    int wv = threadIdx.x >> 6, lane = threadIdx.x & 63;
    int hf = lane >> 5, fp = lane & 31;
    unsigned fp4 = (unsigned)fp * 4u;
    const char* ybp = (const char*)yin;
    int iBase = (blockIdx.x * 8 + wv) * K;
    int cur = 0;
    // prologue: stage node iBase's first chunk
    if (iBase < nlim) {
        int a0 = __builtin_amdgcn_readfirstlane(rp[iBase]);
        int a1 = __builtin_amdgcn_readfirstlane(rp[iBase + 1]);
        int n = a1 - a0;
        if (n > 64) n = 64;
        if (lane < n) estage[wv][cur][lane] = epack[a0 + lane];
    }
    for (int k = 0; k < K; ++k) {
        int i = iBase + k;
        if (i >= nlim) break;
        int e0 = __builtin_amdgcn_readfirstlane(rp[i]);
        int e1 = __builtin_amdgcn_readfirstlane(rp[i + 1]);
        // register-prefetch next node's first chunk (contiguous in epack)
        int2 rnext = make_int2(0, 0);
        int nnext = 0;
        if (k + 1 < K && i + 1 < nlim) {
            int f1 = __builtin_amdgcn_readfirstlane(rp[i + 2]);
            nnext = f1 - e1;
            if (nnext > 64) nnext = 64;
            if (lane < nnext) rnext = epack[e1 + lane];
        }
        float di = dinv[i];
        float ax0 = 0.0f, ay0 = 0.0f, ax1 = 0.0f, ay1 = 0.0f;
        if (hf == 0) {  // self loop (coeff 1), even half only
            unsigned vpk = *(const unsigned*)(ybp + (size_t)i * 128 + fp4);
            __half2 h = *(__half2*)&vpk;
            ax0 = __half2float(h.x);
            ay0 = __half2float(h.y);
        }
        int2* sw = &estage[wv][cur][0];
        for (int base = e0; base < e1; base += 64) {
            int n = e1 - base;
            if (n > 64) n = 64;
            if (base != e0) {  // rare (degree > 64): load on demand
                if (lane < n) sw[lane] = epack[base + lane];
            }
            int n2 = n & ~1;
            int j = 0;
            for (; j + 16 <= n2; j += 16) {  // 8 pairs = 16 rows in flight
                int2 r0 = sw[j + 0 + hf],  r1 = sw[j + 2 + hf];
                int2 r2 = sw[j + 4 + hf],  r3 = sw[j + 6 + hf];
                int2 r4 = sw[j + 8 + hf],  r5 = sw[j + 10 + hf];
                int2 r6 = sw[j + 12 + hf], r7 = sw[j + 14 + hf];
                unsigned v0 = *(const unsigned*)(ybp + ((unsigned)r0.x + fp4));
                unsigned v1 = *(const unsigned*)(ybp + ((unsigned)r1.x + fp4));
                unsigned v2 = *(const unsigned*)(ybp + ((unsigned)r2.x + fp4));
                unsigned v3 = *(const unsigned*)(ybp + ((unsigned)r3.x + fp4));
                unsigned v4 = *(const unsigned*)(ybp + ((unsigned)r4.x + fp4));
                unsigned v5 = *(const unsigned*)(ybp + ((unsigned)r5.x + fp4));
                unsigned v6 = *(const unsigned*)(ybp + ((unsigned)r6.x + fp4));
                unsigned v7 = *(const unsigned*)(ybp + ((unsigned)r7.x + fp4));
                __half2 h0 = *(__half2*)&v0, h1 = *(__half2*)&v1;
                __half2 h2 = *(__half2*)&v2, h3 = *(__half2*)&v3;
                __half2 h4 = *(__half2*)&v4, h5 = *(__half2*)&v5;
                __half2 h6 = *(__half2*)&v6, h7 = *(__half2*)&v7;
                float w0 = __int_as_float(r0.y), w1 = __int_as_float(r1.y);
                float w2 = __int_as_float(r2.y), w3 = __int_as_float(r3.y);
                float w4 = __int_as_float(r4.y), w5 = __int_as_float(r5.y);
                float w6 = __int_as_float(r6.y), w7 = __int_as_float(r7.y);
                ax0 = fmaf(__half2float(h0.x), w0, ax0);
                ay0 = fmaf(__half2float(h0.y), w0, ay0);
                ax1 = fmaf(__half2float(h1.x), w1, ax1);
                ay1 = fmaf(__half2float(h1.y), w1, ay1);
                ax0 = fmaf(__half2float(h2.x), w2, ax0);
                ay0 = fmaf(__half2float(h2.y), w2, ay0);
                ax1 = fmaf(__half2float(h3.x), w3, ax1);
                ay1 = fmaf(__half2float(h3.y), w3, ay1);
                ax0 = fmaf(__half2float(h4.x), w4, ax0);
                ay0 = fmaf(__half2float(h4.y), w4, ay0);
                ax1 = fmaf(__half2float(h5.x), w5, ax1);
                ay1 = fmaf(__half2float(h5.y), w5, ay1);
                ax0 = fmaf(__half2float(h6.x), w6, ax0);
                ay0 = fmaf(__half2float(h6.y), w6, ay0);
                ax1 = fmaf(__half2float(h7.x), w7, ax1);
                ay1 = fmaf(__half2float(h7.y), w7, ay1);
            }
            for (; j + 8 <= n2; j += 8) {  // 4 pairs
                int2 r0 = sw[j + 0 + hf], r1 = sw[j + 2 + hf];
                int2 r2 = sw[j + 4 + hf], r3 = sw[j + 6 + hf];
                unsigned v0 = *(const unsigned*)(ybp + ((unsigned)r0.x + fp4));
                unsigned v1 = *(const unsigned*)(ybp + ((unsigned)r1.x + fp4));
                unsigned v2 = *(const unsigned*)(ybp + ((unsigned)r2.x + fp4));
                unsigned v3 = *(const unsigned*)(ybp + ((unsigned)r3.x + fp4));
                __half2 h0 = *(__half2*)&v0, h1 = *(__half2*)&v1;
                __half2 h2 = *(__half2*)&v2, h3 = *(__half2*)&v3;
                float w0 = __int_as_float(r0.y), w1 = __int_as_float(r1.y);
                float w2 = __int_as_float(r2.y), w3 = __int_as_float(r3.y);
                ax0 = fmaf(__half2float(h0.x), w0, ax0);
                ay0 = fmaf(__half2float(h0.y), w0, ay0);
                ax1 = fmaf(__half2float(h1.x), w1, ax1);
                ay1 = fmaf(__half2float(h1.y), w1, ay1);
                ax0 = fmaf(__half2float(h2.x), w2, ax0);
                ay0 = fmaf(__half2float(h2.y), w2, ay0);
                ax1 = fmaf(__half2float(h3.x), w3, ax1);
                ay1 = fmaf(__half2float(h3.y), w3, ay1);
            }
            for (; j < n2; j += 2) {
                int2 r = sw[j + hf];
                unsigned v = *(const unsigned*)(ybp + ((unsigned)r.x + fp4));
                float wn = __int_as_float(r.y);
                __half2 h = *(__half2*)&v;
                ax0 = fmaf(__half2float(h.x), wn, ax0);
                ay0 = fmaf(__half2float(h.y), wn, ay0);
            }
            if (n2 < n && hf == 0) {  // odd tail edge: even half takes it
                int2 r = sw[n2];
                unsigned v = *(const unsigned*)(ybp + ((unsigned)r.x + fp4));
                float wn = __int_as_float(r.y);
                __half2 h = *(__half2*)&v;
                ax0 = fmaf(__half2float(h.x), wn, ax0);
                ay0 = fmaf(__half2float(h.y), wn, ay0);
            }
        }
        float ax = ax0 + ax1, ay = ay0 + ay1;
        ax += __shfl(ax, lane ^ 32, 64);
        ay += __shfl(ay, lane ^ 32, 64);
        // wave-private aggsh slice: same-wave LDS ordering, no barrier
        if (hf == 0)
            ((float2*)&aggsh[wv * HH])[fp] = make_float2(ax * di, ay * di);
        float o = bsh[lane];
        const float4* a4 = (const float4*)&aggsh[wv * HH];
#pragma unroll
        for (int f0 = 0; f0 < HH; f0 += 4) {
            float4 av = a4[f0 >> 2];  // broadcast read, own-wave slice
            o += av.x * Wsh[(f0 + 0) * HH + lane];
            o += av.y * Wsh[(f0 + 1) * HH + lane];
            o += av.z * Wsh[(f0 + 2) * HH + lane];
            o += av.w * Wsh[(f0 + 3) * HH + lane];
        }
        float sig = 1.0f / (1.0f + __expf(-o));
        if (!HEAD) {
            yout[(size_t)i * HH + lane] = __float2half(sig * di);  // scaled y
        } else {
            aggsh[wv * HH + lane] = sig;  // own-wave slice, no barrier
            if (lane < FOUT) {
                float s = blsh[lane];
                const float* ar = &aggsh[wv * HH];
#pragma unroll
                for (int f = 0; f < HH; ++f) s += ar[f] * Wlsh[f * FOUT + lane];
                outp[(size_t)i * FOUT + lane] = s;
            }
        }
        // commit the prefetched records into the other buffer for node i+1
        if (nnext > 0) {
            cur ^= 1;
            if (lane < nnext) estage[wv][cur][lane] = rnext;
        }
    }
}

extern "C" void kernel_launch(void* const* d_in, const int* in_sizes, int n_in,
                              void* d_out, int out_size, void* d_ws, size_t ws_size,
                              hipStream_t stream) {
    (void)in_sizes; (void)n_in; (void)out_size; (void)ws_size;
    const float* vf = (const float*)d_in[0];
    const int* edges = (const int*)d_in[1];
    const float* w = (const float*)d_in[2];
    const float* W1 = (const float*)d_in[3];
    const float* b1 = (const float*)d_in[4];
    const float* W2 = (const float*)d_in[5];
    const float* b2 = (const float*)d_in[6];
    const float* W3 = (const float*)d_in[7];
    const float* b3 = (const float*)d_in[8];
    const float* W4 = (const float*)d_in[9];
    const float* b4 = (const float*)d_in[10];
    const float* Wl = (const float*)d_in[11];
    const float* bl = (const float*)d_in[12];
    float* out = (float*)d_out;

    const int* src = edges;
    const int* dst = edges + EE;

    // workspace: 256B-aligned regions
    char* base = (char*)d_ws;
    size_t off = 0;
    float* dinv = (float*)(base + off);      off = alignup(off + sizeof(float) * NN);
    int* row_ptr = (int*)(base + off);       off = alignup(off + sizeof(int) * (NN + 1));
    int* bucket_ptr = (int*)(base + off);    off = alignup(off + sizeof(int) * (NBUK + 1));
    int* blockhist = (int*)(base + off);     off = alignup(off + sizeof(int) * NBH * NBUK);
    int2* ebuk = (int2*)(base + off);        off = alignup(off + sizeof(int2) * EE);
    int2* epack = (int2*)(base + off);       off = alignup(off + sizeof(int2) * EE);
    float* vfs = (float*)(base + off);       off = alignup(off + sizeof(float) * (size_t)NN * FINN);
    __half* ya = (__half*)(base + off);      off = alignup(off + sizeof(__half) * (size_t)NN * HH);
    __half* yb = (__half*)(base + off);      off = alignup(off + sizeof(__half) * (size_t)NN * HH);

    // CSR build via two-level bucket sort (no global atomics); csrD also emits vfs
    k_histA<<<NBH, 1024, 0, stream>>>(dst, blockhist);
    k_scanB<<<1, 512, 0, stream>>>(blockhist, bucket_ptr);
    k_scatC<<<NBH, 1024, 0, stream>>>(src, dst, w, blockhist, ebuk);
    k_csrD<<<NBUK, 1024, 0, stream>>>(ebuk, bucket_ptr, row_ptr, dinv, epack, vf, vfs);

    // layer 1 fully fused: gather(6) + 6->64 GEMM + sigmoid (scaled -> ya)
    k_layer1f<<<cdiv(NN, 16), 512, 0, stream>>>(vfs, dinv, row_ptr, epack, W1, b1, ya);

    // layers 2,3 fused (scaled), ping-pong; layer 4 fused + head, 50k nodes only
    k_layer64f<false><<<NN / 32, 512, 0, stream>>>(ya, dinv, row_ptr, epack, W2, b2, yb,
                                                   nullptr, nullptr, nullptr);
    k_layer64f<false><<<NN / 32, 512, 0, stream>>>(yb, dinv, row_ptr, epack, W3, b3, ya,
                                                   nullptr, nullptr, nullptr);
    k_layer64f<true><<<cdiv(NGNB, 32), 512, 0, stream>>>(ya, dinv, row_ptr, epack, W4, b4,
                                                         nullptr, Wl, bl, out);
}